// Round 11
// baseline (237.926 us; speedup 1.0000x reference)
//
#include <hip/hip_runtime.h>

#define I_DIM 16
#define H_DIM 32
#define T_DIM 512
#define B_DIM 4096

typedef __fp16 hf2 __attribute__((ext_vector_type(2)));

__device__ __forceinline__ float fast_tanh(float x) {
    // tanh(x) = 1 - 2/(exp(2x)+1); exp(2x) = exp2(x * 2*log2(e))
    float e = __builtin_amdgcn_exp2f(x * 2.885390081777927f);
    return 1.0f - 2.0f * __builtin_amdgcn_rcpf(e + 1.0f);
}

__device__ __forceinline__ hf2 pack2(float a, float b) {
    hf2 r; r[0] = (__fp16)a; r[1] = (__fp16)b; return r;
}
__device__ __forceinline__ hf2 u2h(unsigned u) {
    union { unsigned u; hf2 h; } c; c.u = u; return c.h;
}

// fold one x-step (4 preloaded float4s) through packed Wih0 row -> scalar
__device__ __forceinline__ float foldf4(float4 a, float4 b, float4 c, float4 d,
                                        const hf2* w, float seed) {
    hf2 p0 = __builtin_amdgcn_cvt_pkrtz(a.x, a.y), p1 = __builtin_amdgcn_cvt_pkrtz(a.z, a.w);
    hf2 p2 = __builtin_amdgcn_cvt_pkrtz(b.x, b.y), p3 = __builtin_amdgcn_cvt_pkrtz(b.z, b.w);
    hf2 p4 = __builtin_amdgcn_cvt_pkrtz(c.x, c.y), p5 = __builtin_amdgcn_cvt_pkrtz(c.z, c.w);
    hf2 p6 = __builtin_amdgcn_cvt_pkrtz(d.x, d.y), p7 = __builtin_amdgcn_cvt_pkrtz(d.z, d.w);
    float s0 = seed, s1 = 0.f, s2 = 0.f, s3 = 0.f;
    s0 = __builtin_amdgcn_fdot2(w[0], p0, s0, false);
    s1 = __builtin_amdgcn_fdot2(w[1], p1, s1, false);
    s2 = __builtin_amdgcn_fdot2(w[2], p2, s2, false);
    s3 = __builtin_amdgcn_fdot2(w[3], p3, s3, false);
    s0 = __builtin_amdgcn_fdot2(w[4], p4, s0, false);
    s1 = __builtin_amdgcn_fdot2(w[5], p5, s1, false);
    s2 = __builtin_amdgcn_fdot2(w[6], p6, s2, false);
    s3 = __builtin_amdgcn_fdot2(w[7], p7, s3, false);
    return (s0 + s1) + (s2 + s3);
}

// one pipelined step for one batch row: layer0(t+1) + layer1(t) dots + tanhs
__device__ __forceinline__ void step_dots(const hf2* whh0p, const hf2* wih1p, const hf2* whh1p,
                                          const hf2* h1v, const hf2* h2v,
                                          float xb, float bias1,
                                          float& h1n, float& h2n) {
    float a0 = xb,    a1 = 0.f, a2 = 0.f, a3 = 0.f;
    float c0 = bias1, c1 = 0.f, c2 = 0.f, c3 = 0.f;
#pragma unroll
    for (int k = 0; k < 16; k += 4) {
        a0 = __builtin_amdgcn_fdot2(whh0p[k+0], h1v[k+0], a0, false);
        a1 = __builtin_amdgcn_fdot2(whh0p[k+1], h1v[k+1], a1, false);
        a2 = __builtin_amdgcn_fdot2(whh0p[k+2], h1v[k+2], a2, false);
        a3 = __builtin_amdgcn_fdot2(whh0p[k+3], h1v[k+3], a3, false);
        c0 = __builtin_amdgcn_fdot2(wih1p[k+0], h1v[k+0], c0, false);
        c1 = __builtin_amdgcn_fdot2(wih1p[k+1], h1v[k+1], c1, false);
        c2 = __builtin_amdgcn_fdot2(wih1p[k+2], h1v[k+2], c2, false);
        c3 = __builtin_amdgcn_fdot2(wih1p[k+3], h1v[k+3], c3, false);
        c0 = __builtin_amdgcn_fdot2(whh1p[k+0], h2v[k+0], c0, false);
        c1 = __builtin_amdgcn_fdot2(whh1p[k+1], h2v[k+1], c1, false);
        c2 = __builtin_amdgcn_fdot2(whh1p[k+2], h2v[k+2], c2, false);
        c3 = __builtin_amdgcn_fdot2(whh1p[k+3], h2v[k+3], c3, false);
    }
    h1n = fast_tanh((a0 + a1) + (a2 + a3));
    h2n = fast_tanh((c0 + c1) + (c2 + c3));
}

__device__ __forceinline__ void read_row(const __fp16* p, hf2* h) {
#pragma unroll
    for (int q = 0; q < 4; ++q) {
        uint4 v = reinterpret_cast<const uint4*>(p)[q];
        h[4*q+0] = u2h(v.x); h[4*q+1] = u2h(v.y);
        h[4*q+2] = u2h(v.z); h[4*q+3] = u2h(v.w);
    }
}

// TWO batch rows per 32-lane half-wave: rows share the per-lane weight regs,
// and the two independent recurrence chains give in-wave ILP that fills the
// LDS-round-trip bubble (round-10 diagnosis: lockstep waves stall together).
__global__ void __launch_bounds__(256)
__attribute__((amdgpu_waves_per_eu(1, 2)))
rnn2_dual_kernel(const float* __restrict__ x,
                 const float* __restrict__ Wih0, const float* __restrict__ Whh0,
                 const float* __restrict__ bih0, const float* __restrict__ bhh0,
                 const float* __restrict__ Wih1, const float* __restrict__ Whh1,
                 const float* __restrict__ bih1, const float* __restrict__ bhh1,
                 const float* __restrict__ fcw, const float* __restrict__ fcb,
                 float* __restrict__ out)
{
    const int tid  = threadIdx.x;
    const int j    = tid & 31;        // output row within H
    const int half = tid >> 5;        // 0..7: half-wave within block
    const int rowbase = blockIdx.x * 16 + half * 2;

    __shared__ __align__(16) __fp16 sh1[16][32];
    __shared__ __align__(16) __fp16 sh2[16][32];
    __fp16* s1A = sh1[half*2+0]; __fp16* s1B = sh1[half*2+1];
    __fp16* s2A = sh2[half*2+0]; __fp16* s2B = sh2[half*2+1];

    // ---- packed per-lane weight rows (shared by both batch rows) ----
    hf2 wih0p[8], whh0p[16], wih1p[16], whh1p[16];
#pragma unroll
    for (int q = 0; q < 4; ++q) {
        float4 v = reinterpret_cast<const float4*>(Wih0 + j * 16)[q];
        wih0p[2*q+0] = pack2(v.x, v.y);
        wih0p[2*q+1] = pack2(v.z, v.w);
    }
#pragma unroll
    for (int q = 0; q < 8; ++q) {
        float4 a = reinterpret_cast<const float4*>(Whh0 + j * 32)[q];
        whh0p[2*q+0] = pack2(a.x, a.y); whh0p[2*q+1] = pack2(a.z, a.w);
        float4 b = reinterpret_cast<const float4*>(Wih1 + j * 32)[q];
        wih1p[2*q+0] = pack2(b.x, b.y); wih1p[2*q+1] = pack2(b.z, b.w);
        float4 c = reinterpret_cast<const float4*>(Whh1 + j * 32)[q];
        whh1p[2*q+0] = pack2(c.x, c.y); whh1p[2*q+1] = pack2(c.z, c.w);
    }
    const float bias0 = bih0[j] + bhh0[j];
    const float bias1 = bih1[j] + bhh1[j];

    const float* xrowA = x + (size_t)(rowbase + 0) * (T_DIM * I_DIM);
    const float* xrowB = x + (size_t)(rowbase + 1) * (T_DIM * I_DIM);

    hf2 h1vA[16], h2vA[16], h1vB[16], h2vB[16];
#pragma unroll
    for (int k = 0; k < 16; ++k) { h2vA[k] = pack2(0.f, 0.f); h2vB[k] = pack2(0.f, 0.f); }

    // ---- prologue: h1(0) per row; xb(1) per row ----
    float xb1A, xb1B;
    {
        const float4* pa = reinterpret_cast<const float4*>(xrowA);
        const float4* pb = reinterpret_cast<const float4*>(xrowB);
        float sA = foldf4(pa[0], pa[1], pa[2], pa[3], wih0p, bias0);
        float sB = foldf4(pb[0], pb[1], pb[2], pb[3], wih0p, bias0);
        s1A[j] = (__fp16)fast_tanh(sA);
        s1B[j] = (__fp16)fast_tanh(sB);
        __builtin_amdgcn_wave_barrier();
        read_row(s1A, h1vA);
        read_row(s1B, h1vB);
        const float4* qa = reinterpret_cast<const float4*>(xrowA + I_DIM);
        const float4* qb = reinterpret_cast<const float4*>(xrowB + I_DIM);
        xb1A = foldf4(qa[0], qa[1], qa[2], qa[3], wih0p, bias0);
        xb1B = foldf4(qb[0], qb[1], qb[2], qb[3], wih0p, bias0);
    }

    // ---- main loop: iter t computes h1(t+1) and h2(t) for both rows ----
#pragma unroll 1
    for (int t = 0; t < T_DIM; ++t) {
        const int tn = (t + 2 < T_DIM) ? (t + 2) : (T_DIM - 1);
        const float4* xpA = reinterpret_cast<const float4*>(xrowA + (size_t)tn * I_DIM);
        const float4* xpB = reinterpret_cast<const float4*>(xrowB + (size_t)tn * I_DIM);
        float4 nA0 = xpA[0], nA1 = xpA[1], nA2 = xpA[2], nA3 = xpA[3];
        float4 nB0 = xpB[0], nB1 = xpB[1], nB2 = xpB[2], nB3 = xpB[3];

        float h1nA, h2nA, h1nB, h2nB;
        step_dots(whh0p, wih1p, whh1p, h1vA, h2vA, xb1A, bias1, h1nA, h2nA);
        step_dots(whh0p, wih1p, whh1p, h1vB, h2vB, xb1B, bias1, h1nB, h2nB);

        s1A[j] = (__fp16)h1nA; s2A[j] = (__fp16)h2nA;
        s1B[j] = (__fp16)h1nB; s2B[j] = (__fp16)h2nB;
        __builtin_amdgcn_wave_barrier();
        read_row(s1A, h1vA); read_row(s2A, h2vA);
        read_row(s1B, h1vB); read_row(s2B, h2vB);

        // x-folds: independent filler that hides the LDS read latency
        xb1A = foldf4(nA0, nA1, nA2, nA3, wih0p, bias0);
        xb1B = foldf4(nB0, nB1, nB2, nB3, wih0p, bias0);
    }

    // ---- final FC on h2(T-1) for both rows ----
    hf2 fwp[16];
#pragma unroll
    for (int q = 0; q < 8; ++q) {
        float4 v = reinterpret_cast<const float4*>(fcw)[q];
        fwp[2*q+0] = pack2(v.x, v.y);
        fwp[2*q+1] = pack2(v.z, v.w);
    }
    float rA0 = 0.f, rA1 = 0.f, rA2 = 0.f, rA3 = 0.f;
    float rB0 = 0.f, rB1 = 0.f, rB2 = 0.f, rB3 = 0.f;
#pragma unroll
    for (int k = 0; k < 16; k += 4) {
        rA0 = __builtin_amdgcn_fdot2(fwp[k+0], h2vA[k+0], rA0, false);
        rA1 = __builtin_amdgcn_fdot2(fwp[k+1], h2vA[k+1], rA1, false);
        rA2 = __builtin_amdgcn_fdot2(fwp[k+2], h2vA[k+2], rA2, false);
        rA3 = __builtin_amdgcn_fdot2(fwp[k+3], h2vA[k+3], rA3, false);
        rB0 = __builtin_amdgcn_fdot2(fwp[k+0], h2vB[k+0], rB0, false);
        rB1 = __builtin_amdgcn_fdot2(fwp[k+1], h2vB[k+1], rB1, false);
        rB2 = __builtin_amdgcn_fdot2(fwp[k+2], h2vB[k+2], rB2, false);
        rB3 = __builtin_amdgcn_fdot2(fwp[k+3], h2vB[k+3], rB3, false);
    }
    if (j == 0) {
        out[rowbase + 0] = fcb[0] + (rA0 + rA1) + (rA2 + rA3);
        out[rowbase + 1] = fcb[0] + (rB0 + rB1) + (rB2 + rB3);
    }
}

extern "C" void kernel_launch(void* const* d_in, const int* in_sizes, int n_in,
                              void* d_out, int out_size, void* d_ws, size_t ws_size,
                              hipStream_t stream) {
    const float* x    = (const float*)d_in[0];
    const float* Wih0 = (const float*)d_in[1];
    const float* Whh0 = (const float*)d_in[2];
    const float* bih0 = (const float*)d_in[3];
    const float* bhh0 = (const float*)d_in[4];
    const float* Wih1 = (const float*)d_in[5];
    const float* Whh1 = (const float*)d_in[6];
    const float* bih1 = (const float*)d_in[7];
    const float* bhh1 = (const float*)d_in[8];
    const float* fcw  = (const float*)d_in[9];
    const float* fcb  = (const float*)d_in[10];
    float* out = (float*)d_out;

    dim3 grid(B_DIM / 16);   // 256 blocks x 8 half-waves x 2 rows = 4096 batch rows
    rnn2_dual_kernel<<<grid, 256, 0, stream>>>(x, Wih0, Whh0, bih0, bhh0,
                                               Wih1, Whh1, bih1, bhh1,
                                               fcw, fcb, out);
}

// Round 12
// 197.771 us; speedup vs baseline: 1.2030x; 1.2030x over previous
//
#include <hip/hip_runtime.h>

#define T_DIM 512
#define I_DIM 16
#define H_DIM 32
#define B_DIM 4096

typedef _Float16 f16x8 __attribute__((ext_vector_type(8)));
typedef float f32x4 __attribute__((ext_vector_type(4)));
typedef __fp16 hf2v __attribute__((ext_vector_type(2)));

union Frag {
    f16x8 v;
    __fp16 e[8];
    uint4 u;
};

__device__ __forceinline__ float fast_tanh(float x) {
    // tanh(x) = 1 - 2/(exp(2x)+1)
    float e = __builtin_amdgcn_exp2f(x * 2.885390081777927f);
    return 1.0f - 2.0f * __builtin_amdgcn_rcpf(e + 1.0f);
}

__device__ __forceinline__ unsigned h2u(hf2v h) {
    union { hf2v h; unsigned u; } c; c.h = h; return c.u;
}

// 8 consecutive f32 -> f16x8 fragment (with scale; scale=0 zeroes the frag)
__device__ __forceinline__ f16x8 loadA8(const float* p, float scale) {
    float4 a = reinterpret_cast<const float4*>(p)[0];
    float4 b = reinterpret_cast<const float4*>(p)[1];
    Frag f;
    hf2v p0 = __builtin_amdgcn_cvt_pkrtz(a.x*scale, a.y*scale);
    hf2v p1 = __builtin_amdgcn_cvt_pkrtz(a.z*scale, a.w*scale);
    hf2v p2 = __builtin_amdgcn_cvt_pkrtz(b.x*scale, b.y*scale);
    hf2v p3 = __builtin_amdgcn_cvt_pkrtz(b.z*scale, b.w*scale);
    f.e[0]=p0[0]; f.e[1]=p0[1]; f.e[2]=p1[0]; f.e[3]=p1[1];
    f.e[4]=p2[0]; f.e[5]=p2[1]; f.e[6]=p3[0]; f.e[7]=p3[1];
    return f.v;
}

__device__ __forceinline__ f16x8 cvt8(float4 a, float4 b) {
    Frag f;
    hf2v p0 = __builtin_amdgcn_cvt_pkrtz(a.x, a.y);
    hf2v p1 = __builtin_amdgcn_cvt_pkrtz(a.z, a.w);
    hf2v p2 = __builtin_amdgcn_cvt_pkrtz(b.x, b.y);
    hf2v p3 = __builtin_amdgcn_cvt_pkrtz(b.z, b.w);
    f.e[0]=p0[0]; f.e[1]=p0[1]; f.e[2]=p1[0]; f.e[3]=p1[1];
    f.e[4]=p2[0]; f.e[5]=p2[1]; f.e[6]=p3[0]; f.e[7]=p3[1];
    return f.v;
}

// One wave per block; wave owns 8 batch columns (cols 8..15 of the 16-wide
// MFMA tile are garbage but column-contained). Per step:
//   D0 = Whh0*h1 + [Wih0*x + b0  (precomputed a step early)]
//   D1 = Wih1*h1 + [Whh1*h2_prev + b1 (precomputed)]
// tanh -> pack f16 -> LDS transpose ([col][row] pad 40) -> B-frags -> repeat.
// Lane maps (16x16x32 f16): A row = lane&15(+16*tile), k = (lane>>4)*8+j;
// B col = lane&15, k same formula (A/B share kmap => any kmap error cancels);
// C/D col = lane&15, row = (lane>>4)*4 + reg  [m89-verified].
__global__ void __launch_bounds__(64)
rnn2_mfma_kernel(const float* __restrict__ x,
                 const float* __restrict__ Wih0, const float* __restrict__ Whh0,
                 const float* __restrict__ bih0, const float* __restrict__ bhh0,
                 const float* __restrict__ Wih1, const float* __restrict__ Whh1,
                 const float* __restrict__ bih1, const float* __restrict__ bhh1,
                 const float* __restrict__ fcw, const float* __restrict__ fcb,
                 float* __restrict__ out)
{
    const int l = threadIdx.x;
    const int c = l & 15;
    const int g = l >> 4;
    const int rowbase = blockIdx.x * 8;
    const size_t xcol = rowbase + (c & 7);          // cols 8-15 duplicate 0-7 (in-bounds)

    __shared__ __fp16 hb1[16][40];                  // [col][h-row], pad 40 for alignment
    __shared__ __fp16 hb2[16][40];

    // ---- weight A-fragments ----
    f16x8 whh0A[2], wih1A[2], whh1A[2], wih0A[2];
#pragma unroll
    for (int tt = 0; tt < 2; ++tt) {
        int row = c + 16*tt;
        whh0A[tt] = loadA8(Whh0 + row*32 + g*8, 1.f);
        wih1A[tt] = loadA8(Wih1 + row*32 + g*8, 1.f);
        whh1A[tt] = loadA8(Whh1 + row*32 + g*8, 1.f);
        // Wih0 is 32x16: k>=16 zero-padded (scale=0 for g>=2; B side garbage*0 safe, finite)
        wih0A[tt] = loadA8(Wih0 + row*16 + (g&1)*8, (g < 2) ? 1.f : 0.f);
    }

    // ---- bias C-inits (D rows g*4+r+16*tt) and fc weights ----
    f32x4 b0C[2], b1C[2];
    float4 fwv[2];
#pragma unroll
    for (int tt = 0; tt < 2; ++tt) {
        int r0 = g*4 + 16*tt;
        float4 bi0 = *reinterpret_cast<const float4*>(bih0 + r0);
        float4 bh0 = *reinterpret_cast<const float4*>(bhh0 + r0);
        b0C[tt][0] = bi0.x + bh0.x; b0C[tt][1] = bi0.y + bh0.y;
        b0C[tt][2] = bi0.z + bh0.z; b0C[tt][3] = bi0.w + bh0.w;
        float4 bi1 = *reinterpret_cast<const float4*>(bih1 + r0);
        float4 bh1 = *reinterpret_cast<const float4*>(bhh1 + r0);
        b1C[tt][0] = bi1.x + bh1.x; b1C[tt][1] = bi1.y + bh1.y;
        b1C[tt][2] = bi1.z + bh1.z; b1C[tt][3] = bi1.w + bh1.w;
        fwv[tt] = *reinterpret_cast<const float4*>(fcw + r0);
    }
    const float fcb0 = fcb[0];

    const float* xlane = x + xcol * (T_DIM * I_DIM) + (g & 1) * 8;

    Frag h1B, h2B;
    f32x4 Xacc[2], L1pre[2];
    float h2f[2][4];

    // ---- prologue: h1(0); Xacc = Wih0*x(1)+b0; L1pre = b1 ----
    {
        float4 a0 = *reinterpret_cast<const float4*>(xlane + 0);
        float4 a1 = *reinterpret_cast<const float4*>(xlane + 4);
        Frag x0; x0.v = cvt8(a0, a1);
        f32x4 D0[2];
        D0[0] = __builtin_amdgcn_mfma_f32_16x16x32_f16(wih0A[0], x0.v, b0C[0], 0, 0, 0);
        D0[1] = __builtin_amdgcn_mfma_f32_16x16x32_f16(wih0A[1], x0.v, b0C[1], 0, 0, 0);
#pragma unroll
        for (int tt = 0; tt < 2; ++tt) {
            float u0 = fast_tanh(D0[tt][0]), u1 = fast_tanh(D0[tt][1]);
            float u2 = fast_tanh(D0[tt][2]), u3 = fast_tanh(D0[tt][3]);
            uint2 w; w.x = h2u(__builtin_amdgcn_cvt_pkrtz(u0, u1));
            w.y = h2u(__builtin_amdgcn_cvt_pkrtz(u2, u3));
            *reinterpret_cast<uint2*>(&hb1[c][16*tt + 4*g]) = w;
        }
        __builtin_amdgcn_wave_barrier();
        h1B.u = *reinterpret_cast<const uint4*>(&hb1[c][8*g]);
        h2B.u = make_uint4(0u, 0u, 0u, 0u);
        float4 b0q = *reinterpret_cast<const float4*>(xlane + 1*I_DIM);
        float4 b1q = *reinterpret_cast<const float4*>(xlane + 1*I_DIM + 4);
        Frag x1; x1.v = cvt8(b0q, b1q);
        Xacc[0] = __builtin_amdgcn_mfma_f32_16x16x32_f16(wih0A[0], x1.v, b0C[0], 0, 0, 0);
        Xacc[1] = __builtin_amdgcn_mfma_f32_16x16x32_f16(wih0A[1], x1.v, b0C[1], 0, 0, 0);
        L1pre[0] = b1C[0];
        L1pre[1] = b1C[1];
    }

    // x prefetch ring: A holds x(t+2) for even t, B for odd t (2-iter depth)
    float4 xA0 = *reinterpret_cast<const float4*>(xlane + 2*I_DIM);
    float4 xA1 = *reinterpret_cast<const float4*>(xlane + 2*I_DIM + 4);
    float4 xB0 = *reinterpret_cast<const float4*>(xlane + 3*I_DIM);
    float4 xB1 = *reinterpret_cast<const float4*>(xlane + 3*I_DIM + 4);

    auto step = [&](int t, float4& P0, float4& P1) {
        // critical-path MFMAs (both depend only on h1B + precomputed accs)
        f32x4 D1_0 = __builtin_amdgcn_mfma_f32_16x16x32_f16(wih1A[0], h1B.v, L1pre[0], 0, 0, 0);
        f32x4 D1_1 = __builtin_amdgcn_mfma_f32_16x16x32_f16(wih1A[1], h1B.v, L1pre[1], 0, 0, 0);
        f32x4 D0_0 = __builtin_amdgcn_mfma_f32_16x16x32_f16(whh0A[0], h1B.v, Xacc[0], 0, 0, 0);
        f32x4 D0_1 = __builtin_amdgcn_mfma_f32_16x16x32_f16(whh0A[1], h1B.v, Xacc[1], 0, 0, 0);

        // consume prefetched x(t+2); immediately reissue buffer for x(t+4)
        Frag xF; xF.v = cvt8(P0, P1);
        int tn = (t + 4 < T_DIM) ? (t + 4) : (T_DIM - 1);
        P0 = *reinterpret_cast<const float4*>(xlane + (size_t)tn * I_DIM);
        P1 = *reinterpret_cast<const float4*>(xlane + (size_t)tn * I_DIM + 4);

        // h1(t+1): tanh -> pack -> LDS
        {
            float u0 = fast_tanh(D0_0[0]), u1 = fast_tanh(D0_0[1]);
            float u2 = fast_tanh(D0_0[2]), u3 = fast_tanh(D0_0[3]);
            uint2 w; w.x = h2u(__builtin_amdgcn_cvt_pkrtz(u0, u1));
            w.y = h2u(__builtin_amdgcn_cvt_pkrtz(u2, u3));
            *reinterpret_cast<uint2*>(&hb1[c][4*g]) = w;
            float v0 = fast_tanh(D0_1[0]), v1 = fast_tanh(D0_1[1]);
            float v2 = fast_tanh(D0_1[2]), v3 = fast_tanh(D0_1[3]);
            uint2 w2; w2.x = h2u(__builtin_amdgcn_cvt_pkrtz(v0, v1));
            w2.y = h2u(__builtin_amdgcn_cvt_pkrtz(v2, v3));
            *reinterpret_cast<uint2*>(&hb1[c][16 + 4*g]) = w2;
        }
        // h2(t): tanh -> pack -> LDS (also kept for the FC epilogue)
        {
            h2f[0][0] = fast_tanh(D1_0[0]); h2f[0][1] = fast_tanh(D1_0[1]);
            h2f[0][2] = fast_tanh(D1_0[2]); h2f[0][3] = fast_tanh(D1_0[3]);
            uint2 w; w.x = h2u(__builtin_amdgcn_cvt_pkrtz(h2f[0][0], h2f[0][1]));
            w.y = h2u(__builtin_amdgcn_cvt_pkrtz(h2f[0][2], h2f[0][3]));
            *reinterpret_cast<uint2*>(&hb2[c][4*g]) = w;
            h2f[1][0] = fast_tanh(D1_1[0]); h2f[1][1] = fast_tanh(D1_1[1]);
            h2f[1][2] = fast_tanh(D1_1[2]); h2f[1][3] = fast_tanh(D1_1[3]);
            uint2 w2; w2.x = h2u(__builtin_amdgcn_cvt_pkrtz(h2f[1][0], h2f[1][1]));
            w2.y = h2u(__builtin_amdgcn_cvt_pkrtz(h2f[1][2], h2f[1][3]));
            *reinterpret_cast<uint2*>(&hb2[c][16 + 4*g]) = w2;
        }
        __builtin_amdgcn_wave_barrier();
        h1B.u = *reinterpret_cast<const uint4*>(&hb1[c][8*g]);
        h2B.u = *reinterpret_cast<const uint4*>(&hb2[c][8*g]);

        // off-critical-path precomputes for next iteration
        Xacc[0]  = __builtin_amdgcn_mfma_f32_16x16x32_f16(wih0A[0], xF.v, b0C[0], 0, 0, 0);
        Xacc[1]  = __builtin_amdgcn_mfma_f32_16x16x32_f16(wih0A[1], xF.v, b0C[1], 0, 0, 0);
        L1pre[0] = __builtin_amdgcn_mfma_f32_16x16x32_f16(whh1A[0], h2B.v, b1C[0], 0, 0, 0);
        L1pre[1] = __builtin_amdgcn_mfma_f32_16x16x32_f16(whh1A[1], h2B.v, b1C[1], 0, 0, 0);
    };

#pragma unroll 1
    for (int tb = 0; tb < T_DIM; tb += 2) {
        step(tb,     xA0, xA1);
        step(tb + 1, xB0, xB1);
    }

    // ---- FC epilogue on h2(T-1): per-lane partial over its 8 rows, then
    // reduce across the 4 lane-groups sharing each column ----
    float acc = fwv[0].x * h2f[0][0] + fwv[0].y * h2f[0][1]
              + fwv[0].z * h2f[0][2] + fwv[0].w * h2f[0][3]
              + fwv[1].x * h2f[1][0] + fwv[1].y * h2f[1][1]
              + fwv[1].z * h2f[1][2] + fwv[1].w * h2f[1][3];
    acc += __shfl_xor(acc, 16, 64);
    acc += __shfl_xor(acc, 32, 64);
    if (l < 8) out[rowbase + l] = acc + fcb0;
}

extern "C" void kernel_launch(void* const* d_in, const int* in_sizes, int n_in,
                              void* d_out, int out_size, void* d_ws, size_t ws_size,
                              hipStream_t stream) {
    const float* x    = (const float*)d_in[0];
    const float* Wih0 = (const float*)d_in[1];
    const float* Whh0 = (const float*)d_in[2];
    const float* bih0 = (const float*)d_in[3];
    const float* bhh0 = (const float*)d_in[4];
    const float* Wih1 = (const float*)d_in[5];
    const float* Whh1 = (const float*)d_in[6];
    const float* bih1 = (const float*)d_in[7];
    const float* bhh1 = (const float*)d_in[8];
    const float* fcw  = (const float*)d_in[9];
    const float* fcb  = (const float*)d_in[10];
    float* out = (float*)d_out;

    dim3 grid(B_DIM / 8);   // 512 blocks x 1 wave, 8 batch columns each
    rnn2_mfma_kernel<<<grid, 64, 0, stream>>>(x, Wih0, Whh0, bih0, bhh0,
                                              Wih1, Whh1, bih1, bhh1,
                                              fcw, fcb, out);
}

// Round 14
// 160.780 us; speedup vs baseline: 1.4798x; 1.2301x over previous
//
#include <hip/hip_runtime.h>

#define T_DIM 512
#define I_DIM 16
#define B_DIM 4096

typedef _Float16 f16x8 __attribute__((ext_vector_type(8)));
typedef float f32x4 __attribute__((ext_vector_type(4)));
typedef __fp16 hf2v __attribute__((ext_vector_type(2)));

union Frag { f16x8 v; __fp16 e[8]; uint4 u; };

__device__ __forceinline__ float fast_tanh(float x) {
    float e = __builtin_amdgcn_exp2f(x * 2.885390081777927f);
    return 1.0f - 2.0f * __builtin_amdgcn_rcpf(e + 1.0f);
}
__device__ __forceinline__ unsigned h2u(hf2v h) {
    union { hf2v h; unsigned u; } c; c.h = h; return c.u;
}
__device__ __forceinline__ f16x8 loadA8(const float* p, float scale) {
    float4 a = reinterpret_cast<const float4*>(p)[0];
    float4 b = reinterpret_cast<const float4*>(p)[1];
    Frag f;
    hf2v p0 = __builtin_amdgcn_cvt_pkrtz(a.x*scale, a.y*scale);
    hf2v p1 = __builtin_amdgcn_cvt_pkrtz(a.z*scale, a.w*scale);
    hf2v p2 = __builtin_amdgcn_cvt_pkrtz(b.x*scale, b.y*scale);
    hf2v p3 = __builtin_amdgcn_cvt_pkrtz(b.z*scale, b.w*scale);
    f.e[0]=p0[0]; f.e[1]=p0[1]; f.e[2]=p1[0]; f.e[3]=p1[1];
    f.e[4]=p2[0]; f.e[5]=p2[1]; f.e[6]=p3[0]; f.e[7]=p3[1];
    return f.v;
}
__device__ __forceinline__ f16x8 cvt8(float4 a, float4 b) {
    Frag f;
    hf2v p0 = __builtin_amdgcn_cvt_pkrtz(a.x, a.y);
    hf2v p1 = __builtin_amdgcn_cvt_pkrtz(a.z, a.w);
    hf2v p2 = __builtin_amdgcn_cvt_pkrtz(b.x, b.y);
    hf2v p3 = __builtin_amdgcn_cvt_pkrtz(b.z, b.w);
    f.e[0]=p0[0]; f.e[1]=p0[1]; f.e[2]=p1[0]; f.e[3]=p1[1];
    f.e[4]=p2[0]; f.e[5]=p2[1]; f.e[6]=p3[0]; f.e[7]=p3[1];
    return f.v;
}

// 4 waves/block, one 8-col batch group (cols dup x2 into 16-wide tile).
// wid 0/1: h1 rows 0-15/16-31 (D0 = Whh0*h1 + Xacc; next Xacc = Wih0*x + b0).
// wid 2/3: h2 rows 0-15/16-31 (D1 = Wih1*h1 + (Whh1*h2prev + b1)).
// Each wave writes ITS row-tile at [c][16*tt + 4*g]  (r13 bug: offset dropped).
// Double-buffered LDS by time-parity; one __syncthreads per step.
__global__ void __launch_bounds__(256)
rnn2_mfma4_kernel(const float* __restrict__ x,
                  const float* __restrict__ Wih0, const float* __restrict__ Whh0,
                  const float* __restrict__ bih0, const float* __restrict__ bhh0,
                  const float* __restrict__ Wih1, const float* __restrict__ Whh1,
                  const float* __restrict__ bih1, const float* __restrict__ bhh1,
                  const float* __restrict__ fcw, const float* __restrict__ fcb,
                  float* __restrict__ out)
{
    const int tid = threadIdx.x;
    const int l   = tid & 63;
    const int wid = tid >> 6;
    const int c   = l & 15;
    const int g   = l >> 4;
    const int tt  = wid & 1;
    const int rowbase = blockIdx.x * 8;
    const size_t xcol = rowbase + (c & 7);

    __shared__ __fp16 hb1[2][16][40];
    __shared__ __fp16 hb2[2][16][40];
    __shared__ float fcred[2][16];

    const int arow = c + 16 * tt;
    const int wslot = 16 * tt + 4 * g;     // this lane's h-write offset in a column

    f16x8 wA0, wA1;
    f32x4 bC;
    float4 fwv;
    if (wid < 2) {
        wA0 = loadA8(Whh0 + arow * 32 + g * 8, 1.f);
        wA1 = loadA8(Wih0 + arow * 16 + (g & 1) * 8, (g < 2) ? 1.f : 0.f);
        int r0 = 4 * g + 16 * tt;
        float4 bi = *reinterpret_cast<const float4*>(bih0 + r0);
        float4 bh = *reinterpret_cast<const float4*>(bhh0 + r0);
        bC[0] = bi.x + bh.x; bC[1] = bi.y + bh.y;
        bC[2] = bi.z + bh.z; bC[3] = bi.w + bh.w;
        fwv = make_float4(0.f, 0.f, 0.f, 0.f);
    } else {
        wA0 = loadA8(Wih1 + arow * 32 + g * 8, 1.f);
        wA1 = loadA8(Whh1 + arow * 32 + g * 8, 1.f);
        int r0 = 4 * g + 16 * tt;
        float4 bi = *reinterpret_cast<const float4*>(bih1 + r0);
        float4 bh = *reinterpret_cast<const float4*>(bhh1 + r0);
        bC[0] = bi.x + bh.x; bC[1] = bi.y + bh.y;
        bC[2] = bi.z + bh.z; bC[3] = bi.w + bh.w;
        fwv = *reinterpret_cast<const float4*>(fcw + r0);
    }

    const float* xlane = x + xcol * (T_DIM * I_DIM) + (g & 1) * 8;

    Frag h1B, h2B;
    f32x4 Xacc;
    float h2f0 = 0.f, h2f1 = 0.f, h2f2 = 0.f, h2f3 = 0.f;
    float4 xA0, xA1, xB0, xB1;

    // ---- prologue ----
    if (wid < 2) {
        float4 a0 = *reinterpret_cast<const float4*>(xlane + 0);
        float4 a1 = *reinterpret_cast<const float4*>(xlane + 4);
        Frag x0; x0.v = cvt8(a0, a1);
        f32x4 D = __builtin_amdgcn_mfma_f32_16x16x32_f16(wA1, x0.v, bC, 0, 0, 0);
        float u0 = fast_tanh(D[0]), u1 = fast_tanh(D[1]);
        float u2 = fast_tanh(D[2]), u3 = fast_tanh(D[3]);
        uint2 w; w.x = h2u(__builtin_amdgcn_cvt_pkrtz(u0, u1));
        w.y = h2u(__builtin_amdgcn_cvt_pkrtz(u2, u3));
        *reinterpret_cast<uint2*>(&hb1[0][c][wslot]) = w;   // h1(0)
        float4 b0 = *reinterpret_cast<const float4*>(xlane + 1 * I_DIM);
        float4 b1 = *reinterpret_cast<const float4*>(xlane + 1 * I_DIM + 4);
        Frag x1; x1.v = cvt8(b0, b1);
        Xacc = __builtin_amdgcn_mfma_f32_16x16x32_f16(wA1, x1.v, bC, 0, 0, 0); // x(1)+b0
        xA0 = *reinterpret_cast<const float4*>(xlane + 2 * I_DIM);
        xA1 = *reinterpret_cast<const float4*>(xlane + 2 * I_DIM + 4);
        xB0 = *reinterpret_cast<const float4*>(xlane + 3 * I_DIM);
        xB1 = *reinterpret_cast<const float4*>(xlane + 3 * I_DIM + 4);
    } else {
        uint2 z; z.x = 0u; z.y = 0u;
        *reinterpret_cast<uint2*>(&hb2[1][c][wslot]) = z;   // h2(-1) = 0
    }
    __syncthreads();

    // ---- main loop: iter t reads h1(t)/h2(t-1), writes h1(t+1)/h2(t) ----
#pragma unroll 1
    for (int tb = 0; tb < T_DIM; tb += 2) {
        // ===== even step t=tb: h1 in buf0, h2prev in buf1 =====
        h1B.u = *reinterpret_cast<const uint4*>(&hb1[0][c][8 * g]);
        if (wid < 2) {
            f32x4 D = __builtin_amdgcn_mfma_f32_16x16x32_f16(wA0, h1B.v, Xacc, 0, 0, 0);
            Frag xF; xF.v = cvt8(xA0, xA1);
            int tn = (tb + 4 < T_DIM) ? (tb + 4) : (T_DIM - 1);
            xA0 = *reinterpret_cast<const float4*>(xlane + (size_t)tn * I_DIM);
            xA1 = *reinterpret_cast<const float4*>(xlane + (size_t)tn * I_DIM + 4);
            Xacc = __builtin_amdgcn_mfma_f32_16x16x32_f16(wA1, xF.v, bC, 0, 0, 0);
            float u0 = fast_tanh(D[0]), u1 = fast_tanh(D[1]);
            float u2 = fast_tanh(D[2]), u3 = fast_tanh(D[3]);
            uint2 w; w.x = h2u(__builtin_amdgcn_cvt_pkrtz(u0, u1));
            w.y = h2u(__builtin_amdgcn_cvt_pkrtz(u2, u3));
            *reinterpret_cast<uint2*>(&hb1[1][c][wslot]) = w;      // h1(t+1)
        } else {
            h2B.u = *reinterpret_cast<const uint4*>(&hb2[1][c][8 * g]);
            f32x4 t1 = __builtin_amdgcn_mfma_f32_16x16x32_f16(wA1, h2B.v, bC, 0, 0, 0);
            f32x4 D  = __builtin_amdgcn_mfma_f32_16x16x32_f16(wA0, h1B.v, t1, 0, 0, 0);
            h2f0 = fast_tanh(D[0]); h2f1 = fast_tanh(D[1]);
            h2f2 = fast_tanh(D[2]); h2f3 = fast_tanh(D[3]);
            uint2 w; w.x = h2u(__builtin_amdgcn_cvt_pkrtz(h2f0, h2f1));
            w.y = h2u(__builtin_amdgcn_cvt_pkrtz(h2f2, h2f3));
            *reinterpret_cast<uint2*>(&hb2[0][c][wslot]) = w;      // h2(t)
        }
        __syncthreads();

        // ===== odd step t=tb+1: h1 in buf1, h2prev in buf0 =====
        h1B.u = *reinterpret_cast<const uint4*>(&hb1[1][c][8 * g]);
        if (wid < 2) {
            f32x4 D = __builtin_amdgcn_mfma_f32_16x16x32_f16(wA0, h1B.v, Xacc, 0, 0, 0);
            Frag xF; xF.v = cvt8(xB0, xB1);
            int tn = (tb + 5 < T_DIM) ? (tb + 5) : (T_DIM - 1);
            xB0 = *reinterpret_cast<const float4*>(xlane + (size_t)tn * I_DIM);
            xB1 = *reinterpret_cast<const float4*>(xlane + (size_t)tn * I_DIM + 4);
            Xacc = __builtin_amdgcn_mfma_f32_16x16x32_f16(wA1, xF.v, bC, 0, 0, 0);
            float u0 = fast_tanh(D[0]), u1 = fast_tanh(D[1]);
            float u2 = fast_tanh(D[2]), u3 = fast_tanh(D[3]);
            uint2 w; w.x = h2u(__builtin_amdgcn_cvt_pkrtz(u0, u1));
            w.y = h2u(__builtin_amdgcn_cvt_pkrtz(u2, u3));
            *reinterpret_cast<uint2*>(&hb1[0][c][wslot]) = w;      // h1(t+1)
        } else {
            h2B.u = *reinterpret_cast<const uint4*>(&hb2[0][c][8 * g]);
            f32x4 t1 = __builtin_amdgcn_mfma_f32_16x16x32_f16(wA1, h2B.v, bC, 0, 0, 0);
            f32x4 D  = __builtin_amdgcn_mfma_f32_16x16x32_f16(wA0, h1B.v, t1, 0, 0, 0);
            h2f0 = fast_tanh(D[0]); h2f1 = fast_tanh(D[1]);
            h2f2 = fast_tanh(D[2]); h2f3 = fast_tanh(D[3]);
            uint2 w; w.x = h2u(__builtin_amdgcn_cvt_pkrtz(h2f0, h2f1));
            w.y = h2u(__builtin_amdgcn_cvt_pkrtz(h2f2, h2f3));
            *reinterpret_cast<uint2*>(&hb2[1][c][wslot]) = w;      // h2(t)
        }
        __syncthreads();
    }

    // ---- FC epilogue: w2/3 hold h2(T-1) rows in regs ----
    if (wid >= 2) {
        float part = fwv.x * h2f0 + fwv.y * h2f1 + fwv.z * h2f2 + fwv.w * h2f3;
        part += __shfl_xor(part, 16, 64);
        part += __shfl_xor(part, 32, 64);
        if (l < 16) fcred[wid - 2][l] = part;
    }
    __syncthreads();
    if (wid == 0 && l < 8) out[rowbase + l] = fcred[0][l] + fcred[1][l] + fcb[0];
}

extern "C" void kernel_launch(void* const* d_in, const int* in_sizes, int n_in,
                              void* d_out, int out_size, void* d_ws, size_t ws_size,
                              hipStream_t stream) {
    const float* x    = (const float*)d_in[0];
    const float* Wih0 = (const float*)d_in[1];
    const float* Whh0 = (const float*)d_in[2];
    const float* bih0 = (const float*)d_in[3];
    const float* bhh0 = (const float*)d_in[4];
    const float* Wih1 = (const float*)d_in[5];
    const float* Whh1 = (const float*)d_in[6];
    const float* bih1 = (const float*)d_in[7];
    const float* bhh1 = (const float*)d_in[8];
    const float* fcw  = (const float*)d_in[9];
    const float* fcb  = (const float*)d_in[10];
    float* out = (float*)d_out;

    dim3 grid(B_DIM / 8);   // 512 blocks x 4 waves (2048 waves = 2/SIMD)
    rnn2_mfma4_kernel<<<grid, 256, 0, stream>>>(x, Wih0, Whh0, bih0, bhh0,
                                                Wih1, Whh1, bih1, bhh1,
                                                fcw, fcb, out);
}